// Round 6
// baseline (9747.309 us; speedup 1.0000x reference)
//
#include <hip/hip_runtime.h>

#define B_ 64
#define T_ 256
#define H_ 1024
#define D_ 409
#define NFLAG 1024
#define NSLOT 513   // slot s holds h after step s (s=1..512); slot 0 unused

typedef _Float16 h8 __attribute__((ext_vector_type(8)));
typedef float f4 __attribute__((ext_vector_type(4)));
typedef unsigned u4v __attribute__((ext_vector_type(4)));
typedef int i4v __attribute__((ext_vector_type(4)));

__device__ __forceinline__ float sigf(float x) {
  return 1.f / (1.f + __expf(-x));
}
__device__ __forceinline__ float tanhf_(float x) {
  return 1.f - 2.f / (1.f + __expf(2.f * x));   // saturates correctly
}

// ---------------- prep: pack x and pred_W into fp16 MFMA fragment layouts ---
// frag (16x16x32): lane l holds row/col (l&15), k = 8*(l>>4)+e
__global__ __launch_bounds__(256) void prep_kernel(
    const float* __restrict__ inp, const float* __restrict__ Pw,
    _Float16* __restrict__ xP, _Float16* __restrict__ PP,
    int* __restrict__ flags)
{
  const int NX = 256 * 4 * 13 * 64;   // x frags: [t][r16][kc][lane] x 8
  const int NP = 26 * 32 * 64;        // pred frags: [nt][kc][lane] x 8
  int gid = blockIdx.x * 256 + threadIdx.x;
  if (gid < NFLAG) flags[gid] = 0;    // stream-ordered before recur launch
  if (gid < NX) {
    int lane = gid & 63; int q = gid >> 6;
    int kc = q % 13; q /= 13;
    int mt = q & 3;  int t = q >> 2;
    const float* src = inp + ((size_t)(16 * mt + (lane & 15)) * T_ + t) * D_;
    int k0 = kc * 32 + 8 * (lane >> 4);
    h8 v;
#pragma unroll
    for (int e = 0; e < 8; ++e) {
      int k = k0 + e;
      v[e] = (k < D_) ? (_Float16)src[k] : (_Float16)0.f;
    }
    *(h8*)(xP + (size_t)gid * 8) = v;
  } else if (gid < NX + NP) {
    int r = gid - NX;
    int lane = r & 63; int q = r >> 6;
    int kc = q & 31; int nt = q >> 5;
    int n = nt * 16 + (lane & 15);
    int k0 = kc * 32 + 8 * (lane >> 4);
    h8 v;
#pragma unroll
    for (int e = 0; e < 8; ++e)
      v[e] = (n < D_) ? (_Float16)Pw[(size_t)n * H_ + k0 + e] : (_Float16)0.f;
    *(h8*)(PP + (size_t)r * 8) = v;
  }
}

// counted wait + scheduling fence (rule #18)
#define VMW(N) do { \
  asm volatile("s_waitcnt vmcnt(" #N ")" ::: "memory"); \
  __builtin_amdgcn_sched_barrier(0); \
} while (0)

// issue one kc-group (4 x dwordx4) of h B-frags into ring slot G&3
#define HISS(G, O0, O1, O2, O3) \
  asm volatile( \
    "global_load_dwordx4 %0, %4, %5 offset:" #O0 "\n\t" \
    "global_load_dwordx4 %1, %4, %5 offset:" #O1 "\n\t" \
    "global_load_dwordx4 %2, %4, %5 offset:" #O2 "\n\t" \
    "global_load_dwordx4 %3, %4, %5 offset:" #O3 "\n\t" \
    : "=&v"(BH[(G) & 3][0]), "=&v"(BH[(G) & 3][1]), \
      "=&v"(BH[(G) & 3][2]), "=&v"(BH[(G) & 3][3]) \
    : "v"(voff_h), "s"(hb) : "memory")

// consume one kc-group: A=weights (hi+lo), B=h; acc chain = in-group index
#define HCONS(G) do { \
  _Pragma("unroll") \
  for (int i_ = 0; i_ < 4; ++i_) { \
    h8 hv_ = __builtin_bit_cast(h8, BH[(G) & 3][i_]); \
    accP[i_] = __builtin_amdgcn_mfma_f32_16x16x32_f16(Whi[4 * (G) + i_], hv_, accP[i_], 0, 0, 0); \
    accP[i_] = __builtin_amdgcn_mfma_f32_16x16x32_f16(Wlo[4 * (G) + i_], hv_, accP[i_], 0, 0, 0); \
  } \
} while (0)

// ---------------- persistent recurrent kernel: 256 WGs x 256 threads --------
// Operand-swapped MFMA: A = weight frag (M=16 gate-cols, unit-major 4u+g),
// B = state frag (N=16 batch rows). Wave (w,mw) owns units
// [u16*16+mw*4, +4) x batch rows [16*r16, +16) x FULL K. Lane's 4 acc regs =
// the 4 gates of one (b,u): gate math fully in-register, NO LDS, NO barriers.
// r16 = (w&7)>>1: all WGs on an XCD read the same 16 h rows (L2/L1 sharing).
// Per-wave flags; publish ack overlapped with next step's x loads (vmcnt(13)).
__global__ __launch_bounds__(256, 1) void recur_kernel(
    const float* __restrict__ eWhh, const float* __restrict__ eb,
    const float* __restrict__ dWhh, const float* __restrict__ db,
    const float* __restrict__ eWih, const float* __restrict__ dWih,
    const _Float16* __restrict__ xP, _Float16* __restrict__ ring,
    int* __restrict__ flags, float* __restrict__ latents)
{
  const int tid  = threadIdx.x;
  const int w    = blockIdx.x;
  const int mw   = tid >> 6;
  const int lane = tid & 63;
  const int ci   = lane & 15;
  const int q    = lane >> 4;
  const int r16  = (w & 7) >> 1;                 // XCD-uniform batch block
  const int u16  = ((w >> 3) << 1) | (w & 1);    // unit block 0..63
  const int ubase = u16 * 16 + mw * 4;
  // A-frag: lane supplies gate-col r=ci -> W row = gate*H + unit
  const int wr   = (ci & 3) * H_ + ubase + (ci >> 2);
  // lane's output element
  const int brow = 16 * r16 + ci;
  const int uout = ubase + q;
  const int fidx = r16 * 256 + u16 * 4 + mw;     // this wave's flag

  const unsigned voff_h  = (unsigned)((brow * H_ + 8 * q) * 2);
  const unsigned voff_st = (unsigned)((brow * H_ + uout) * 2);
  const unsigned voff_f  = (unsigned)(r16 * 1024 + lane * 16);
  const unsigned voff_x  = (unsigned)(lane * 16);

  h8 Whi[32], Wlo[32], Ih[13];
  f4 bias4;
  float c_reg = 0.f;

#pragma unroll 1
  for (int s = 1; s <= 512; ++s) {
    if (s == 1 || s == 257) {
      const float* Whh = (s == 1) ? eWhh : dWhh;
      const float* Wih = (s == 1) ? eWih : dWih;
      const float* bb  = (s == 1) ? eb : db;
#pragma unroll 4
      for (int kc = 0; kc < 32; ++kc) {
        const float* p = Whh + (size_t)wr * H_ + kc * 32 + 8 * q;
#pragma unroll
        for (int e = 0; e < 8; ++e) {
          float wf = p[e];
          _Float16 hi = (_Float16)wf;
          Whi[kc][e] = hi;
          Wlo[kc][e] = (_Float16)(wf - (float)hi);
        }
      }
#pragma unroll
      for (int kc = 0; kc < 13; ++kc) {
        int k0 = kc * 32 + 8 * q;
#pragma unroll
        for (int e = 0; e < 8; ++e) {
          int k = k0 + e;
          Ih[kc][e] = (k < D_) ? (_Float16)Wih[(size_t)wr * D_ + k] : (_Float16)0.f;
        }
      }
#pragma unroll
      for (int g2 = 0; g2 < 4; ++g2) bias4[g2] = bb[g2 * H_ + uout];
      asm volatile("s_waitcnt vmcnt(0)" ::: "memory");
    }

    const bool have_h = (s > 1);
    const int  t_x    = (s <= 256) ? (s - 1) : (s - 258);
    const bool have_x = (t_x >= 0);

    f4 accP[4], accX[2];
#pragma unroll
    for (int j = 0; j < 4; ++j) { f4 z = {0.f, 0.f, 0.f, 0.f}; accP[j] = z; }
    accX[0] = accP[0]; accX[1] = accP[0];

    u4v xB[13];
    if (have_x) {
      const _Float16* xb0 = xP + ((size_t)(t_x * 4 + r16) * 13 + 0) * 512;
      const _Float16* xb1 = xb0 + 4 * 512;
      const _Float16* xb2 = xb0 + 8 * 512;
      const _Float16* xb3 = xb0 + 12 * 512;
      asm volatile(
        "global_load_dwordx4 %0, %13, %14\n\t"
        "global_load_dwordx4 %1, %13, %14 offset:1024\n\t"
        "global_load_dwordx4 %2, %13, %14 offset:2048\n\t"
        "global_load_dwordx4 %3, %13, %14 offset:3072\n\t"
        "global_load_dwordx4 %4, %13, %15\n\t"
        "global_load_dwordx4 %5, %13, %15 offset:1024\n\t"
        "global_load_dwordx4 %6, %13, %15 offset:2048\n\t"
        "global_load_dwordx4 %7, %13, %15 offset:3072\n\t"
        "global_load_dwordx4 %8, %13, %16\n\t"
        "global_load_dwordx4 %9, %13, %16 offset:1024\n\t"
        "global_load_dwordx4 %10, %13, %16 offset:2048\n\t"
        "global_load_dwordx4 %11, %13, %16 offset:3072\n\t"
        "global_load_dwordx4 %12, %13, %17\n\t"
        : "=&v"(xB[0]), "=&v"(xB[1]), "=&v"(xB[2]), "=&v"(xB[3]),
          "=&v"(xB[4]), "=&v"(xB[5]), "=&v"(xB[6]), "=&v"(xB[7]),
          "=&v"(xB[8]), "=&v"(xB[9]), "=&v"(xB[10]), "=&v"(xB[11]),
          "=&v"(xB[12])
        : "v"(voff_x), "s"(xb0), "s"(xb1), "s"(xb2), "s"(xb3)
        : "memory");
    }

    // publish previous step: h-store ack under the x loads, then flag
    if (s > 1) {
      if (have_x) { VMW(13); } else { VMW(0); }
      if (lane == 0)
        __hip_atomic_store(flags + fidx, s - 1, __ATOMIC_RELAXED,
                           __HIP_MEMORY_SCOPE_AGENT);
    }

    if (have_x) {
      if (s > 1) { VMW(1); } else { VMW(0); }
#pragma unroll
      for (int kc = 0; kc < 13; ++kc) {
        h8 xv = __builtin_bit_cast(h8, xB[kc]);
        accX[kc & 1] = __builtin_amdgcn_mfma_f32_16x16x32_f16(Ih[kc], xv, accX[kc & 1], 0, 0, 0);
      }
    }

    if (have_h) {
      // wait for the 256 producer-waves of this batch block (4 flags/lane)
      const int target = s - 1;
      int it = 0;
      while (true) {
        i4v fv;
        asm volatile("global_load_dwordx4 %0, %1, %2 sc0 sc1\n\t"
                     "s_waitcnt vmcnt(0)"
                     : "=v"(fv) : "v"(voff_f), "s"(flags) : "memory");
        int mn0 = fv[0] < fv[1] ? fv[0] : fv[1];
        int mn1 = fv[2] < fv[3] ? fv[2] : fv[3];
        int mn = mn0 < mn1 ? mn0 : mn1;
        if (!__any(mn < target)) break;
        if (++it > (1 << 14)) break;   // safety valve (shows as bad absmax)
      }
      __builtin_amdgcn_sched_barrier(0);

      const _Float16* hb = ring + (size_t)(s - 1) * (B_ * H_);
      u4v BH[4][4];
      HISS(0, 0, 64, 128, 192);
      HISS(1, 256, 320, 384, 448);
      HISS(2, 512, 576, 640, 704);
      HISS(3, 768, 832, 896, 960);
      VMW(12); HCONS(0); HISS(4, 1024, 1088, 1152, 1216);
      VMW(12); HCONS(1); HISS(5, 1280, 1344, 1408, 1472);
      VMW(12); HCONS(2); HISS(6, 1536, 1600, 1664, 1728);
      VMW(12); HCONS(3); HISS(7, 1792, 1856, 1920, 1984);
      VMW(12); HCONS(4);
      VMW(8);  HCONS(5);
      VMW(4);  HCONS(6);
      VMW(0);  HCONS(7);
    }

    // epilogue: lane holds gates i,f,g,o of (brow, uout) in the 4 acc regs
    f4 tot = accP[0] + accP[1] + accP[2] + accP[3] + accX[0] + accX[1] + bias4;
    float cold = have_h ? c_reg : 0.f;
    float cn = sigf(tot[1]) * cold + sigf(tot[0]) * tanhf_(tot[2]);
    float hn = sigf(tot[3]) * tanhf_(cn);
    c_reg = cn;
    _Float16 h16 = (_Float16)hn;
    unsigned short hu = __builtin_bit_cast(unsigned short, h16);
    // fire-and-forget device-visible publish (ack counted next iteration)
    __hip_atomic_store(
        (unsigned short*)(ring + (size_t)s * (B_ * H_)) + (brow * H_ + uout),
        hu, __ATOMIC_RELAXED, __HIP_MEMORY_SCOPE_AGENT);
    if (s == 256)
      latents[brow * H_ + uout] = hn;
  }
}

// ---------------- prediction head: [16384,1024] @ [1024,409] + bias ---------
// hs = ring slots 257..512 (decoder outputs), layout [t][b][H] fp16
__global__ __launch_bounds__(256) void pred_kernel(
    const _Float16* __restrict__ hs, const _Float16* __restrict__ PP,
    const float* __restrict__ pb, float* __restrict__ outseq)
{
  int wt = blockIdx.x * 4 + (threadIdx.x >> 6);
  int lane = threadIdx.x & 63;
  int nt = wt % 26, mt = wt / 26;
  int i = lane & 15, q = lane >> 4;
  int n = nt * 16 + i;
  float bias = (n < D_) ? pb[n] : 0.f;
  f4 acc = {bias, bias, bias, bias};
  int R = mt * 16;
#pragma unroll 4
  for (int kc = 0; kc < 32; ++kc) {
    h8 a = *(const h8*)(hs + (size_t)(R + i) * H_ + kc * 32 + 8 * q);
    h8 b = *(const h8*)(PP + ((size_t)(nt * 32 + kc) * 64 + lane) * 8);
    acc = __builtin_amdgcn_mfma_f32_16x16x32_f16(a, b, acc, 0, 0, 0);
  }
#pragma unroll
  for (int r = 0; r < 4; ++r) {
    int row = R + 4 * q + r;       // row = t*64 + b
    int t = row >> 6, bb = row & 63;
    if (n < D_) outseq[((size_t)bb * T_ + t) * D_ + n] = acc[r];
  }
}

extern "C" void kernel_launch(void* const* d_in, const int* in_sizes, int n_in,
                              void* d_out, int out_size, void* d_ws, size_t ws_size,
                              hipStream_t stream) {
  const float* inp  = (const float*)d_in[0];
  const float* eWih = (const float*)d_in[1];
  const float* eWhh = (const float*)d_in[2];
  const float* eb   = (const float*)d_in[3];
  const float* dWih = (const float*)d_in[4];
  const float* dWhh = (const float*)d_in[5];
  const float* db   = (const float*)d_in[6];
  const float* pW   = (const float*)d_in[7];
  const float* pb   = (const float*)d_in[8];
  float* out = (float*)d_out;
  float* latents = out;              // [1,64,1024]
  float* seq = out + 64 * 1024;      // [64,256,409]

  char* ws = (char*)d_ws;
  size_t off = 0;
  auto alloc = [&](size_t bytes) {
    void* p = ws + off;
    off = (off + bytes + 255) & ~(size_t)255;
    return p;
  };
  _Float16* xP   = (_Float16*)alloc((size_t)256 * 4 * 13 * 64 * 8 * 2);
  _Float16* PP   = (_Float16*)alloc((size_t)26 * 32 * 64 * 8 * 2);
  _Float16* ring = (_Float16*)alloc((size_t)NSLOT * B_ * H_ * 2);
  int* flags     = (int*)alloc(NFLAG * 4);

  hipLaunchKernelGGL(prep_kernel, dim3(3536), dim3(256), 0, stream,
                     inp, pW, xP, PP, flags);
  hipLaunchKernelGGL(recur_kernel, dim3(256), dim3(256), 0, stream,
                     eWhh, eb, dWhh, db, eWih, dWih, xP, ring, flags, latents);
  hipLaunchKernelGGL(pred_kernel, dim3(6656), dim3(256), 0, stream,
                     ring + (size_t)257 * B_ * H_, PP, pb, seq);
}